// Round 4
// baseline (1017.341 us; speedup 1.0000x reference)
//
#include <hip/hip_runtime.h>

#define C_N 64
#define I_N 64
#define R_N 36
#define L_N 40
#define D_N 1024
#define S_N 256

#define ATT_LD 40
#define P_LD   72
#define SIMC_LD 264   // 256 data + 8 pad (16B-aligned rows)

// ws layout (shorts): converted inputs only (~16.8 MB)
#define OFF_CAP 2359296
#define OFF_WT  4980736
#define OFF_IMT 5242880
#define OFF_END 8388608   // 64 shorts zero slack (img_t k-overread of last row)

typedef float f4 __attribute__((ext_vector_type(4)));
typedef short s16x8 __attribute__((ext_vector_type(8)));

__device__ __forceinline__ unsigned short f2bs(float f) {
    union { float f; unsigned u; } v; v.f = f;
    unsigned r = v.u + 0x7FFFu + ((v.u >> 16) & 1u);
    return (unsigned short)(r >> 16);
}
__device__ __forceinline__ float bs2f(unsigned short s) {
    union { unsigned u; float f; } v; v.u = ((unsigned)s) << 16;
    return v.f;
}
__device__ __forceinline__ void async16(const unsigned short* g, unsigned short* l) {
    __builtin_amdgcn_global_load_lds(
        (const __attribute__((address_space(1))) unsigned int*)g,
        (__attribute__((address_space(3))) unsigned int*)l, 16, 0, 0);
}

// ---------------- K0: converts ----------------
__global__ void k_convert(const float* __restrict__ img, const float* __restrict__ cap,
                          const float* __restrict__ W, unsigned short* __restrict__ ws) {
    int t = blockIdx.x * 256 + threadIdx.x;
    if (t < I_N * R_N * D_N) ws[t] = f2bs(img[t]);
    if (t < C_N * L_N * D_N) ws[OFF_CAP + t] = f2bs(cap[t]);
    if (t < D_N * S_N) {                       // W[d][s] -> Wt[s][d]
        int d = t >> 8, s = t & 255;
        ws[OFF_WT + s * D_N + d] = f2bs(W[t]);
    }
    if (t < I_N * R_N * D_N) {                 // img_t [i][d][r48]
        int i = t / (R_N * D_N), r = (t / D_N) % R_N, d = t % D_N;
        ws[OFF_IMT + (i * D_N + d) * 48 + r] = f2bs(img[t]);
    }
    if (t < I_N * D_N * 12) {                  // img_t zero rows 36..47
        int i = t / (D_N * 12), d = (t / 12) % D_N, rr = t % 12;
        ws[OFF_IMT + (i * D_N + d) * 48 + 36 + rr] = 0;
    }
    if (t < 64) ws[OFF_END + t] = 0;
}

// ---------------- fused: block = (c,i); c fastest for XCD/L2 locality ----------------
__global__ __launch_bounds__(512, 2)
void k_fused(const unsigned short* __restrict__ img_b,
             const unsigned short* __restrict__ cap_b,
             const unsigned short* __restrict__ wt,
             const unsigned short* __restrict__ img_t,
             const int* __restrict__ cap_lens,
             const float* __restrict__ bias,
             float* __restrict__ out) {
    __shared__ __align__(16) float          s_attn[48 * ATT_LD];      //  7680 B
    __shared__ __align__(16) unsigned short s_p[48 * P_LD];           //  6912 B
    __shared__ __align__(16) unsigned short s_sim[48 * SIMC_LD];      // 25344 B
    __shared__ __align__(16) unsigned short s_wt[256 * 64];           // 32768 B
    __shared__ float s_norm[48];
    __shared__ float s_norm2[48];

    const int c = blockIdx.x, i = blockIdx.y;
    const int tid  = threadIdx.x;
    const int wave = tid >> 6, lane = tid & 63;
    const int q = lane >> 4, ln16 = lane & 15;
    const int lrow8 = lane >> 3;
    const int cgg = ((lane & 7) ^ (lane >> 3)) << 3;   // swizzled col chunk (shorts)

    const unsigned short* capc = cap_b + c * (L_N * D_N);
    const unsigned short* imgc = img_b + i * (R_N * D_N);
    const unsigned short* imtc = img_t + (size_t)i * D_N * 48;

    // ---- phase 0: init ----
    for (int k = tid; k < 48 * ATT_LD; k += 512) s_attn[k] = 0.f;
    for (int k = tid; k < 48 * P_LD; k += 512) s_p[k] = 0;
    for (int k = tid; k < 8 * SIMC_LD; k += 512) s_sim[40 * SIMC_LD + k] = 0;  // rows 40..47
    if (tid < 48) { s_norm[tid] = 0.f; s_norm2[tid] = 0.f; }
    __syncthreads();

    // ---- phase 1: GEMM1 attn^T[l][r] = cap . img^T, K split over 8 waves ----
    {
        f4 acc[3][3] = {};
        const int kw = wave * 128;
        #pragma unroll
        for (int ks = 0; ks < 4; ++ks) {
            const int kb = kw + ks * 32 + q * 8;
            s16x8 af[3], bfr[3];
            #pragma unroll
            for (int mt = 0; mt < 3; ++mt) {
                int l = mt * 16 + ln16;
                af[mt] = (l < L_N) ? *(const s16x8*)(capc + l * D_N + kb) : (s16x8)0;
            }
            #pragma unroll
            for (int nt = 0; nt < 3; ++nt) {
                int r = nt * 16 + ln16;
                bfr[nt] = (r < R_N) ? *(const s16x8*)(imgc + r * D_N + kb) : (s16x8)0;
            }
            #pragma unroll
            for (int mt = 0; mt < 3; ++mt)
                #pragma unroll
                for (int nt = 0; nt < 3; ++nt)
                    acc[mt][nt] = __builtin_amdgcn_mfma_f32_16x16x32_bf16(af[mt], bfr[nt], acc[mt][nt], 0, 0, 0);
        }
        #pragma unroll
        for (int mt = 0; mt < 3; ++mt)
            #pragma unroll
            for (int nt = 0; nt < 3; ++nt)
                #pragma unroll
                for (int j = 0; j < 4; ++j) {
                    int l = mt * 16 + q * 4 + j;
                    int r = nt * 16 + ln16;
                    if (l < L_N && r < R_N) atomicAdd(&s_attn[l * ATT_LD + r], acc[mt][nt][j]);
                }
    }
    __syncthreads();

    // ---- phase 2a: leaky_relu + l2norm over words ----
    if (tid < R_N) {
        float ss = 0.f;
        #pragma unroll
        for (int l = 0; l < L_N; ++l) {
            float v = s_attn[l * ATT_LD + tid];
            v = (v > 0.f) ? v : 0.1f * v;
            s_attn[l * ATT_LD + tid] = v;
            ss += v * v;
        }
        float inv = 1.f / (sqrtf(ss) + 1e-8f);
        #pragma unroll
        for (int l = 0; l < L_N; ++l) s_attn[l * ATT_LD + tid] *= inv;
    }
    __syncthreads();
    // ---- phase 2b: softmax over regions -> s_p bf16 ----
    if (tid < L_N) {
        float mx = -1e30f;
        #pragma unroll
        for (int r = 0; r < R_N; ++r) mx = fmaxf(mx, 9.f * s_attn[tid * ATT_LD + r]);
        float sum = 0.f;
        float ex[R_N];
        #pragma unroll
        for (int r = 0; r < R_N; ++r) {
            float e = __expf(9.f * s_attn[tid * ATT_LD + r] - mx);
            ex[r] = e; sum += e;
        }
        float inv = 1.f / sum;
        #pragma unroll
        for (int r = 0; r < R_N; ++r) s_p[tid * P_LD + r] = f2bs(ex[r] * inv);
    }
    __syncthreads();

    // ---- phase 3: GEMM2 once, full wc slice in registers (wave owns 128 d-cols) ----
    f4 a2[4][3][2] = {};
    {
        #pragma unroll
        for (int s4 = 0; s4 < 4; ++s4) {
            const int dbase = wave * 128 + s4 * 32;
            #pragma unroll
            for (int ks = 0; ks < 2; ++ks) {
                const int kb = ks * 32 + q * 8;
                s16x8 pf[3];
                #pragma unroll
                for (int mt = 0; mt < 3; ++mt)
                    pf[mt] = *(const s16x8*)(s_p + (mt * 16 + ln16) * P_LD + kb);
                #pragma unroll
                for (int nt = 0; nt < 2; ++nt) {
                    const int dcol = dbase + nt * 16 + ln16;
                    s16x8 bfr = *(const s16x8*)(imtc + dcol * 48 + kb);
                    #pragma unroll
                    for (int mt = 0; mt < 3; ++mt)
                        a2[s4][mt][nt] = __builtin_amdgcn_mfma_f32_16x16x32_bf16(pf[mt], bfr, a2[s4][mt][nt], 0, 0, 0);
                }
            }
        }
        float rs[3][4] = {};
        #pragma unroll
        for (int s4 = 0; s4 < 4; ++s4)
            #pragma unroll
            for (int mt = 0; mt < 3; ++mt)
                #pragma unroll
                for (int j = 0; j < 4; ++j)
                    rs[mt][j] += a2[s4][mt][0][j] * a2[s4][mt][0][j]
                               + a2[s4][mt][1][j] * a2[s4][mt][1][j];
        #pragma unroll
        for (int mt = 0; mt < 3; ++mt)
            #pragma unroll
            for (int j = 0; j < 4; ++j) {
                float s = rs[mt][j];
                #pragma unroll
                for (int o = 1; o < 16; o <<= 1) s += __shfl_xor(s, o, 64);
                if (ln16 == 0) atomicAdd(&s_norm[mt * 16 + q * 4 + j], s);
            }
    }
    __syncthreads();
    if (tid < 48) s_norm[tid] = 1.f / (sqrtf(s_norm[tid]) + 1e-8f);
    __syncthreads();

    // ---- phase 4: per quarter — sim from registers -> LDS, GEMM3 with staged Wt ----
    f4 acc3[3][2] = {};
    #pragma unroll 1
    for (int Q = 0; Q < 4; ++Q) {
        if ((wave >> 1) == Q) {   // waves 2Q,2Q+1 own this quarter's wc
            const int cbase = (wave & 1) * 128;
            #pragma unroll
            for (int s4 = 0; s4 < 4; ++s4)
                #pragma unroll
                for (int mt = 0; mt < 3; ++mt)
                    #pragma unroll
                    for (int j = 0; j < 4; ++j) {
                        const int l = mt * 16 + q * 4 + j;
                        if (l < L_N) {
                            const float inv = s_norm[l];
                            #pragma unroll
                            for (int nt = 0; nt < 2; ++nt) {
                                const int cl = cbase + s4 * 32 + nt * 16 + ln16;
                                float dv = a2[s4][mt][nt][j] * inv
                                         - bs2f(capc[l * D_N + Q * 256 + cl]);
                                s_sim[l * SIMC_LD + cl] = f2bs(dv * dv);
                            }
                        }
                    }
        }
        __syncthreads();
        #pragma unroll 1
        for (int kc = 0; kc < 4; ++kc) {
            const int kofs = Q * 256 + kc * 64;
            #pragma unroll
            for (int it = 0; it < 4; ++it) {
                int row = it * 64 + wave * 8 + lrow8;
                async16(wt + (size_t)row * D_N + kofs + cgg,
                        s_wt + (it * 512 + wave * 64) * 8);
            }
            __syncthreads();
            #pragma unroll
            for (int ks = 0; ks < 2; ++ks) {
                const int g = ks * 4 + q;
                s16x8 af[3], bf[2];
                #pragma unroll
                for (int mt = 0; mt < 3; ++mt)
                    af[mt] = *(const s16x8*)(s_sim + (mt * 16 + ln16) * SIMC_LD + kc * 64 + ks * 32 + q * 8);
                #pragma unroll
                for (int u = 0; u < 2; ++u) {
                    const int rr = wave * 32 + u * 16 + ln16;
                    bf[u] = *(const s16x8*)(s_wt + rr * 64 + ((g ^ (rr & 7)) << 3));
                }
                #pragma unroll
                for (int mt = 0; mt < 3; ++mt)
                    #pragma unroll
                    for (int u = 0; u < 2; ++u)
                        acc3[mt][u] = __builtin_amdgcn_mfma_f32_16x16x32_bf16(af[mt], bf[u], acc3[mt][u], 0, 0, 0);
            }
            __syncthreads();
        }
    }

    // ---- epilogue: +b, relu, l2norm over s, mask, store ----
    const int clen = cap_lens[c];
    float bv[2];
    #pragma unroll
    for (int u = 0; u < 2; ++u) bv[u] = bias[wave * 32 + u * 16 + ln16];
    #pragma unroll
    for (int mt = 0; mt < 3; ++mt)
        #pragma unroll
        for (int j = 0; j < 4; ++j) {
            float s = 0.f;
            #pragma unroll
            for (int u = 0; u < 2; ++u) {
                float v = acc3[mt][u][j] + bv[u];
                v = fmaxf(v, 0.f);
                acc3[mt][u][j] = v;
                s += v * v;
            }
            #pragma unroll
            for (int o = 1; o < 16; o <<= 1) s += __shfl_xor(s, o, 64);
            if (ln16 == 0) atomicAdd(&s_norm2[mt * 16 + q * 4 + j], s);
        }
    __syncthreads();
    if (tid < 48) s_norm2[tid] = 1.f / (sqrtf(s_norm2[tid]) + 1e-8f);
    __syncthreads();
    float* outc = out + (size_t)((c * I_N + i) * L_N) * S_N;
    #pragma unroll
    for (int mt = 0; mt < 3; ++mt)
        #pragma unroll
        for (int j = 0; j < 4; ++j) {
            const int l = mt * 16 + q * 4 + j;
            if (l < L_N) {
                const float sc = (l < clen) ? s_norm2[l] : 0.f;
                #pragma unroll
                for (int u = 0; u < 2; ++u)
                    outc[l * S_N + wave * 32 + u * 16 + ln16] = acc3[mt][u][j] * sc;
            }
        }
}

extern "C" void kernel_launch(void* const* d_in, const int* in_sizes, int n_in,
                              void* d_out, int out_size, void* d_ws, size_t ws_size,
                              hipStream_t stream) {
    const float* img  = (const float*)d_in[0];
    const float* cap  = (const float*)d_in[1];
    const int*   lens = (const int*)d_in[2];
    const float* W    = (const float*)d_in[5];
    const float* bias = (const float*)d_in[6];
    float* out = (float*)d_out;
    unsigned short* ws = (unsigned short*)d_ws;

    k_convert<<<10240, 256, 0, stream>>>(img, cap, W, ws);

    dim3 grid(C_N, I_N);   // c fastest -> XCD k holds c%8==k; img slice L2-hot per i
    k_fused<<<grid, 512, 0, stream>>>(ws, ws + OFF_CAP, ws + OFF_WT, ws + OFF_IMT,
                                      lens, bias, out);
}